// Round 7
// baseline (62.095 us; speedup 1.0000x reference)
//
#include <hip/hip_runtime.h>
#include <hip/hip_bf16.h>

// Problem constants (match reference setup_inputs)
#define B 256
#define L 512
#define H 256
#define K 512
#define RELV 50000          // rel_emb rows

// ws layout (bytes):
//   [0, 131072)       : ushort encbf[B][H]      bf16 enc_last, b-major (128 KB)
//   [262144, ...)     : ushort P2[RELV][B]      bf16 scores, row-major (25.6 MB)
#define WS_ENC_OFF 0
#define WS_P2_OFF  (256 * 1024)
#define WS_NEEDED  (WS_P2_OFF + (size_t)RELV * B * 2)

typedef __attribute__((ext_vector_type(8))) short bf16x8;
typedef __attribute__((ext_vector_type(4))) float f32x4;

__device__ __forceinline__ ushort f2bf(float f) {
    unsigned u = __float_as_uint(f);
    u += 0x7fffu + ((u >> 16) & 1u);      // round-to-nearest-even
    return (ushort)(u >> 16);
}

// single-instruction packed cast: v_cvt_pk_bf16_f32 (gfx950)
__device__ __forceinline__ unsigned pk2(float x, float y) {
    union { __hip_bfloat162 h; unsigned u; } cv;
    cv.h = __float22bfloat162_rn(make_float2(x, y));   // .x -> low16, .y -> high16
    return cv.u;
}

// ---- kernel 1: last-non-pad gather + bf16 cast of enc_last (grid B) ----
__global__ __launch_bounds__(256)
void enc_cast(const int* __restrict__ entities,
              const float* __restrict__ encoded,
              ushort* __restrict__ encbf)
{
    const int b = blockIdx.x, t = threadIdx.x, lane = t & 63;
    __shared__ int s_count;
    if (t == 0) s_count = 0;
    __syncthreads();
    unsigned long long m0 = __ballot(entities[b * L + t] != 0);
    unsigned long long m1 = __ballot(entities[b * L + t + 256] != 0);
    if (lane == 0) atomicAdd(&s_count, __popcll(m0) + __popcll(m1));
    __syncthreads();
    int idx = s_count - 1;
    idx = max(0, min(L - 1, idx));        // matches JAX clip-mode gather
    encbf[b * H + t] = f2bf(encoded[((size_t)(b * L + idx)) * H + t]);
}

// ---- kernel 2: P2[r][b] = rel_emb[r] . enc_last[b], bf16 MFMA GEMM ----
// block = 4 waves; BM = 64 rel rows (4 strips of 16); wave w owns cols w*64..+63.
// B-fragments (enc) persistent in registers: [kb=0..7][cf=0..3].
// Fragment mappings bench-verified in R6 (absmax 7.8e-3 pass).
__global__ __launch_bounds__(256)
void gemm_p2(const float* __restrict__ rel_emb,
             const ushort* __restrict__ encbf,
             ushort* __restrict__ P2)
{
    const int t    = threadIdx.x;
    const int lane = t & 63;
    const int w    = t >> 6;
    const int r0   = blockIdx.x * 64;
    const int colbase = w * 64;
    const int lrow = lane & 15;    // A row / B col / D col within 16
    const int lkb  = lane >> 4;    // k sub-block (8 elems each)

    // persistent enc fragments: lane holds encbf[col][kb*32 + lkb*8 .. +7]
    bf16x8 Bf[8][4];
    #pragma unroll
    for (int kb = 0; kb < 8; ++kb)
        #pragma unroll
        for (int cf = 0; cf < 4; ++cf) {
            const ushort* p = encbf + (size_t)(colbase + cf * 16 + lrow) * H
                            + kb * 32 + lkb * 8;
            Bf[kb][cf] = *(const bf16x8*)p;
        }

    for (int strip = 0; strip < 4; ++strip) {
        int arow = r0 + strip * 16 + lrow;
        arow = min(arow, RELV - 1);                      // tail clamp (loads only)
        const float* ap = rel_emb + (size_t)arow * H + lkb * 8;

        f32x4 acc0 = {0.f, 0.f, 0.f, 0.f};
        f32x4 acc1 = {0.f, 0.f, 0.f, 0.f};
        f32x4 acc2 = {0.f, 0.f, 0.f, 0.f};
        f32x4 acc3 = {0.f, 0.f, 0.f, 0.f};

        #pragma unroll
        for (int kb = 0; kb < 8; ++kb) {
            float4 a0 = *(const float4*)(ap + kb * 32);
            float4 a1 = *(const float4*)(ap + kb * 32 + 4);
            union { bf16x8 v; unsigned u[4]; } af;
            af.u[0] = pk2(a0.x, a0.y);
            af.u[1] = pk2(a0.z, a0.w);
            af.u[2] = pk2(a1.x, a1.y);
            af.u[3] = pk2(a1.z, a1.w);

            acc0 = __builtin_amdgcn_mfma_f32_16x16x32_bf16(af.v, Bf[kb][0], acc0, 0, 0, 0);
            acc1 = __builtin_amdgcn_mfma_f32_16x16x32_bf16(af.v, Bf[kb][1], acc1, 0, 0, 0);
            acc2 = __builtin_amdgcn_mfma_f32_16x16x32_bf16(af.v, Bf[kb][2], acc2, 0, 0, 0);
            acc3 = __builtin_amdgcn_mfma_f32_16x16x32_bf16(af.v, Bf[kb][3], acc3, 0, 0, 0);
        }

        // D mapping: col = lane&15, row = (lane>>4)*4 + j  (m89/R6-verified)
        const int srow = r0 + strip * 16 + lkb * 4;
        #pragma unroll
        for (int j = 0; j < 4; ++j) {
            const int rr = srow + j;
            if (rr < RELV) {
                ushort* pr = P2 + (size_t)rr * B + colbase + lrow;
                pr[0]  = f2bf(acc0[j]);
                pr[16] = f2bf(acc1[j]);
                pr[32] = f2bf(acc2[j]);
                pr[48] = f2bf(acc3[j]);
            }
        }
    }
}

// ---- kernel 3: ragged gather of precomputed scores (grid B*K/256) ----
__global__ __launch_bounds__(256)
void gather_out(const int* __restrict__ actions,
                const int* __restrict__ action_keys,
                const ushort* __restrict__ P2,
                float* __restrict__ out)
{
    const int tid = blockIdx.x * 256 + threadIdx.x;   // tid = b*K + k
    const int b   = tid >> 9;                         // K == 512
    const int r   = actions[action_keys[tid]];
    const unsigned bits = ((unsigned)P2[(size_t)r * B + b]) << 16;
    out[tid] = __uint_as_float(bits);
}

// ---- fallback (proven R2 kernel) if ws too small for P2 ----
#define CHUNKS 8
#define KPB (K / CHUNKS)
#define KPW (KPB / 4)
#define KPG (KPW / 4)

__global__ __launch_bounds__(256)
void preds_fused_kernel(const int* __restrict__ entities,
                        const int* __restrict__ actions,
                        const int* __restrict__ action_keys,
                        const float* __restrict__ encoded,
                        const float* __restrict__ rel_emb,
                        float* __restrict__ out)
{
    const int blk   = blockIdx.x;
    const int b     = blk >> 3;
    const int chunk = blk & 7;
    const int t     = threadIdx.x;
    const int lane  = t & 63;
    const int wave  = t >> 6;
    const int gid   = lane >> 4;
    const int gl    = lane & 15;

    __shared__ int s_count;
    if (t == 0) s_count = 0;
    __syncthreads();
    unsigned long long m0 = __ballot(entities[b * L + t] != 0);
    unsigned long long m1 = __ballot(entities[b * L + t + 256] != 0);
    if (lane == 0) atomicAdd(&s_count, __popcll(m0) + __popcll(m1));
    __syncthreads();
    int idx = s_count - 1;
    idx = max(0, min(L - 1, idx));

    const int kw = chunk * KPB + wave * KPW;
    const int* ak = action_keys + b * K;
    int av = 0;
    if (lane < KPW) av = actions[ak[kw + lane]];

    const float* encrow = &encoded[((size_t)(b * L + idx)) * H];
    const float4 e0 = *(const float4*)&encrow[gl * 4];
    const float4 e1 = *(const float4*)&encrow[gl * 4 + 64];
    const float4 e2 = *(const float4*)&encrow[gl * 4 + 128];
    const float4 e3 = *(const float4*)&encrow[gl * 4 + 192];

    #pragma unroll
    for (int i = 0; i < KPG; i += 2) {
        const int o0 = gid * KPG + i;
        const int o1 = o0 + 1;
        const int a0 = __shfl(av, o0, 64);
        const int a1 = __shfl(av, o1, 64);
        const float* r0 = &rel_emb[(size_t)a0 * H];
        const float* r1 = &rel_emb[(size_t)a1 * H];

        float4 r00 = *(const float4*)&r0[gl * 4];
        float4 r01 = *(const float4*)&r0[gl * 4 + 64];
        float4 r02 = *(const float4*)&r0[gl * 4 + 128];
        float4 r03 = *(const float4*)&r0[gl * 4 + 192];
        float4 r10 = *(const float4*)&r1[gl * 4];
        float4 r11 = *(const float4*)&r1[gl * 4 + 64];
        float4 r12 = *(const float4*)&r1[gl * 4 + 128];
        float4 r13 = *(const float4*)&r1[gl * 4 + 192];

        float p0 = r00.x * e0.x + r00.y * e0.y + r00.z * e0.z + r00.w * e0.w;
        p0 += r01.x * e1.x + r01.y * e1.y + r01.z * e1.z + r01.w * e1.w;
        p0 += r02.x * e2.x + r02.y * e2.y + r02.z * e2.z + r02.w * e2.w;
        p0 += r03.x * e3.x + r03.y * e3.y + r03.z * e3.z + r03.w * e3.w;
        float p1 = r10.x * e0.x + r10.y * e0.y + r10.z * e0.z + r10.w * e0.w;
        p1 += r11.x * e1.x + r11.y * e1.y + r11.z * e1.z + r11.w * e1.w;
        p1 += r12.x * e2.x + r12.y * e2.y + r12.z * e2.z + r12.w * e2.w;
        p1 += r13.x * e3.x + r13.y * e3.y + r13.z * e3.z + r13.w * e3.w;

        #pragma unroll
        for (int off = 1; off < 16; off <<= 1) {
            p0 += __shfl_xor(p0, off, 64);
            p1 += __shfl_xor(p1, off, 64);
        }
        if (gl == 0) {
            out[b * K + kw + o0] = p0;
            out[b * K + kw + o1] = p1;
        }
    }
}

extern "C" void kernel_launch(void* const* d_in, const int* in_sizes, int n_in,
                              void* d_out, int out_size, void* d_ws, size_t ws_size,
                              hipStream_t stream)
{
    const int*   entities    = (const int*)d_in[0];
    // d_in[1] = relations (unused by the reference computation)
    const int*   actions     = (const int*)d_in[2];
    const int*   action_keys = (const int*)d_in[3];
    const float* encoded     = (const float*)d_in[4];
    const float* rel_emb     = (const float*)d_in[5];
    float*       out         = (float*)d_out;

    if (ws_size >= WS_NEEDED) {
        ushort* encbf = (ushort*)((char*)d_ws + WS_ENC_OFF);
        ushort* P2    = (ushort*)((char*)d_ws + WS_P2_OFF);

        hipLaunchKernelGGL(enc_cast, dim3(B), dim3(256), 0, stream,
                           entities, encoded, encbf);
        hipLaunchKernelGGL(gemm_p2, dim3((RELV + 63) / 64), dim3(256), 0, stream,
                           rel_emb, encbf, P2);
        hipLaunchKernelGGL(gather_out, dim3(B * K / 256), dim3(256), 0, stream,
                           actions, action_keys, P2, out);
    } else {
        hipLaunchKernelGGL(preds_fused_kernel, dim3(B * CHUNKS), dim3(256), 0, stream,
                           entities, actions, action_keys, encoded, rel_emb, out);
    }
}

// Round 8
// 33.501 us; speedup vs baseline: 1.8535x; 1.8535x over previous
//
#include <hip/hip_runtime.h>
#include <hip/hip_bf16.h>

// Problem constants (match reference setup_inputs)
#define B 256
#define L 512
#define H 256
#define K 512
#define RELV 50000          // rel_emb rows

// ws layout (bytes):
//   [0, 131072)     : ushort encfrag[16][8][64][8]  enc_last bf16 in MFMA-fragment
//                     order: [ct][kb][lane][e] = enc[col=16ct+(lane&15)][k=kb*32+(lane>>4)*8+e]
//   [262144, ...)   : ushort P2[RELV][B]            bf16 scores, row-major (25.6 MB)
#define WS_ENC_OFF 0
#define WS_P2_OFF  (256 * 1024)
#define WS_NEEDED  (WS_P2_OFF + (size_t)RELV * B * 2)

typedef __attribute__((ext_vector_type(8))) short bf16x8;
typedef __attribute__((ext_vector_type(4))) float f32x4;

__device__ __forceinline__ ushort f2bf(float f) {
    unsigned u = __float_as_uint(f);
    u += 0x7fffu + ((u >> 16) & 1u);      // round-to-nearest-even
    return (ushort)(u >> 16);
}

// single-instruction packed cast: v_cvt_pk_bf16_f32 (gfx950)
__device__ __forceinline__ unsigned pk2(float x, float y) {
    union { __hip_bfloat162 h; unsigned u; } cv;
    cv.h = __float22bfloat162_rn(make_float2(x, y));   // .x -> low16, .y -> high16
    return cv.u;
}

// ---- kernel 1: last-non-pad gather + bf16 cast into fragment-order table ----
__global__ __launch_bounds__(256)
void enc_cast(const int* __restrict__ entities,
              const float* __restrict__ encoded,
              ushort* __restrict__ encfrag)
{
    const int b = blockIdx.x, t = threadIdx.x, lane = t & 63;
    __shared__ int s_count;
    if (t == 0) s_count = 0;
    __syncthreads();
    unsigned long long m0 = __ballot(entities[b * L + t] != 0);
    unsigned long long m1 = __ballot(entities[b * L + t + 256] != 0);
    if (lane == 0) atomicAdd(&s_count, __popcll(m0) + __popcll(m1));
    __syncthreads();
    int idx = s_count - 1;
    idx = max(0, min(L - 1, idx));        // matches JAX clip-mode gather

    const int h = t;
    const ushort val = f2bf(encoded[((size_t)(b * L + idx)) * H + h]);
    // fragment-order address
    const int ct = b >> 4;
    const int kb = h >> 5;
    const int hi = (h >> 3) & 3;
    const int e  = h & 7;
    const int lf = (b & 15) | (hi << 4);
    encfrag[((((ct * 8 + kb) * 64) + lf) << 3) | e] = val;
}

// ---- kernel 2: P2[r][b] = rel_emb[r] . enc_last[b], LDS-staged bf16 MFMA GEMM
// block = 4 waves, BM = 64 rel rows, BN = 256 (wave w owns cols w*64..+63), K = 256.
// A staged via XOR-swizzled LDS (coalesced global loads); B-frags coalesced from encfrag.
// MFMA fragment mappings bench-verified in R6/R7 (absmax 7.8e-3 pass).
__global__ __launch_bounds__(256)
void gemm_p2(const float* __restrict__ rel_emb,
             const ushort* __restrict__ encfrag,
             ushort* __restrict__ P2)
{
    __shared__ ushort As[64 * 256];        // 32 KB bf16 A-tile, swizzled rows

    const int t    = threadIdx.x;
    const int lane = t & 63;
    const int w    = t >> 6;
    const int r0   = blockIdx.x * 64;

    // ---- stage A: 8 iters x 8 floats/thread, coalesced 1 KB/wave-instr ----
    #pragma unroll
    for (int it = 0; it < 8; ++it) {
        const int row = it * 8 + (t >> 5);          // 0..63
        const int kc  = (t & 31) * 8;               // 0..248
        const int arow = min(r0 + row, RELV - 1);   // tail clamp (loads only)
        const float4 a0 = *(const float4*)&rel_emb[(size_t)arow * H + kc];
        const float4 a1 = *(const float4*)&rel_emb[(size_t)arow * H + kc + 4];
        union { bf16x8 v; unsigned u[4]; } af;
        af.u[0] = pk2(a0.x, a0.y);
        af.u[1] = pk2(a0.z, a0.w);
        af.u[2] = pk2(a1.x, a1.y);
        af.u[3] = pk2(a1.z, a1.w);
        // XOR-swizzled LDS byte address (16B-aligned swizzle within row)
        const int us = row * 256 + (((kc * 2) ^ ((row & 7) << 4)) >> 1);
        *(bf16x8*)&As[us] = af.v;
    }
    __syncthreads();

    // ---- compute: acc[strip][cf], fully unrolled (static indexing) ----
    const int lrow = lane & 15;    // A row / B col / D col within 16
    const int lkb  = lane >> 4;    // k sub-block (8 elems each)
    const int colbase = w * 64;
    const int ct0 = colbase >> 4;

    f32x4 acc[4][4];
    #pragma unroll
    for (int s = 0; s < 4; ++s)
        #pragma unroll
        for (int c = 0; c < 4; ++c)
            acc[s][c] = (f32x4){0.f, 0.f, 0.f, 0.f};

    #pragma unroll
    for (int kb = 0; kb < 8; ++kb) {
        // B-fragments: coalesced 1 KB loads from fragment-order table (L2-hot)
        bf16x8 Bf0 = *(const bf16x8*)&encfrag[(((ct0 + 0) * 8 + kb) * 64 + lane) * 8];
        bf16x8 Bf1 = *(const bf16x8*)&encfrag[(((ct0 + 1) * 8 + kb) * 64 + lane) * 8];
        bf16x8 Bf2 = *(const bf16x8*)&encfrag[(((ct0 + 2) * 8 + kb) * 64 + lane) * 8];
        bf16x8 Bf3 = *(const bf16x8*)&encfrag[(((ct0 + 3) * 8 + kb) * 64 + lane) * 8];

        #pragma unroll
        for (int s = 0; s < 4; ++s) {
            const int row = s * 16 + lrow;
            const int kbyte = (kb * 64 + lkb * 16) ^ ((lrow & 7) << 4);
            const bf16x8 a = *(const bf16x8*)&As[row * 256 + (kbyte >> 1)];
            acc[s][0] = __builtin_amdgcn_mfma_f32_16x16x32_bf16(a, Bf0, acc[s][0], 0, 0, 0);
            acc[s][1] = __builtin_amdgcn_mfma_f32_16x16x32_bf16(a, Bf1, acc[s][1], 0, 0, 0);
            acc[s][2] = __builtin_amdgcn_mfma_f32_16x16x32_bf16(a, Bf2, acc[s][2], 0, 0, 0);
            acc[s][3] = __builtin_amdgcn_mfma_f32_16x16x32_bf16(a, Bf3, acc[s][3], 0, 0, 0);
        }
    }

    // ---- epilogue: D col = lane&15, row = lkb*4 + j (m89/R6-verified) ----
    #pragma unroll
    for (int s = 0; s < 4; ++s) {
        const int srow = r0 + s * 16 + lkb * 4;
        #pragma unroll
        for (int j = 0; j < 4; ++j) {
            const int rr = srow + j;
            if (rr < RELV) {
                ushort* pr = P2 + (size_t)rr * B + colbase + lrow;
                pr[0]  = f2bf(acc[s][0][j]);
                pr[16] = f2bf(acc[s][1][j]);
                pr[32] = f2bf(acc[s][2][j]);
                pr[48] = f2bf(acc[s][3][j]);
            }
        }
    }
}

// ---- kernel 3: ragged gather of precomputed scores (grid B*K/256) ----
__global__ __launch_bounds__(256)
void gather_out(const int* __restrict__ actions,
                const int* __restrict__ action_keys,
                const ushort* __restrict__ P2,
                float* __restrict__ out)
{
    const int tid = blockIdx.x * 256 + threadIdx.x;   // tid = b*K + k
    const int b   = tid >> 9;                         // K == 512
    const int r   = actions[action_keys[tid]];
    const unsigned bits = ((unsigned)P2[(size_t)r * B + b]) << 16;
    out[tid] = __uint_as_float(bits);
}

// ---- fallback (proven R2 kernel) if ws too small for P2 ----
#define CHUNKS 8
#define KPB (K / CHUNKS)
#define KPW (KPB / 4)
#define KPG (KPW / 4)

__global__ __launch_bounds__(256)
void preds_fused_kernel(const int* __restrict__ entities,
                        const int* __restrict__ actions,
                        const int* __restrict__ action_keys,
                        const float* __restrict__ encoded,
                        const float* __restrict__ rel_emb,
                        float* __restrict__ out)
{
    const int blk   = blockIdx.x;
    const int b     = blk >> 3;
    const int chunk = blk & 7;
    const int t     = threadIdx.x;
    const int lane  = t & 63;
    const int wave  = t >> 6;
    const int gid   = lane >> 4;
    const int gl    = lane & 15;

    __shared__ int s_count;
    if (t == 0) s_count = 0;
    __syncthreads();
    unsigned long long m0 = __ballot(entities[b * L + t] != 0);
    unsigned long long m1 = __ballot(entities[b * L + t + 256] != 0);
    if (lane == 0) atomicAdd(&s_count, __popcll(m0) + __popcll(m1));
    __syncthreads();
    int idx = s_count - 1;
    idx = max(0, min(L - 1, idx));

    const int kw = chunk * KPB + wave * KPW;
    const int* ak = action_keys + b * K;
    int av = 0;
    if (lane < KPW) av = actions[ak[kw + lane]];

    const float* encrow = &encoded[((size_t)(b * L + idx)) * H];
    const float4 e0 = *(const float4*)&encrow[gl * 4];
    const float4 e1 = *(const float4*)&encrow[gl * 4 + 64];
    const float4 e2 = *(const float4*)&encrow[gl * 4 + 128];
    const float4 e3 = *(const float4*)&encrow[gl * 4 + 192];

    #pragma unroll
    for (int i = 0; i < KPG; i += 2) {
        const int o0 = gid * KPG + i;
        const int o1 = o0 + 1;
        const int a0 = __shfl(av, o0, 64);
        const int a1 = __shfl(av, o1, 64);
        const float* r0 = &rel_emb[(size_t)a0 * H];
        const float* r1 = &rel_emb[(size_t)a1 * H];

        float4 r00 = *(const float4*)&r0[gl * 4];
        float4 r01 = *(const float4*)&r0[gl * 4 + 64];
        float4 r02 = *(const float4*)&r0[gl * 4 + 128];
        float4 r03 = *(const float4*)&r0[gl * 4 + 192];
        float4 r10 = *(const float4*)&r1[gl * 4];
        float4 r11 = *(const float4*)&r1[gl * 4 + 64];
        float4 r12 = *(const float4*)&r1[gl * 4 + 128];
        float4 r13 = *(const float4*)&r1[gl * 4 + 192];

        float p0 = r00.x * e0.x + r00.y * e0.y + r00.z * e0.z + r00.w * e0.w;
        p0 += r01.x * e1.x + r01.y * e1.y + r01.z * e1.z + r01.w * e1.w;
        p0 += r02.x * e2.x + r02.y * e2.y + r02.z * e2.z + r02.w * e2.w;
        p0 += r03.x * e3.x + r03.y * e3.y + r03.z * e3.z + r03.w * e3.w;
        float p1 = r10.x * e0.x + r10.y * e0.y + r10.z * e0.z + r10.w * e0.w;
        p1 += r11.x * e1.x + r11.y * e1.y + r11.z * e1.z + r11.w * e1.w;
        p1 += r12.x * e2.x + r12.y * e2.y + r12.z * e2.z + r12.w * e2.w;
        p1 += r13.x * e3.x + r13.y * e3.y + r13.z * e3.z + r13.w * e3.w;

        #pragma unroll
        for (int off = 1; off < 16; off <<= 1) {
            p0 += __shfl_xor(p0, off, 64);
            p1 += __shfl_xor(p1, off, 64);
        }
        if (gl == 0) {
            out[b * K + kw + o0] = p0;
            out[b * K + kw + o1] = p1;
        }
    }
}

extern "C" void kernel_launch(void* const* d_in, const int* in_sizes, int n_in,
                              void* d_out, int out_size, void* d_ws, size_t ws_size,
                              hipStream_t stream)
{
    const int*   entities    = (const int*)d_in[0];
    // d_in[1] = relations (unused by the reference computation)
    const int*   actions     = (const int*)d_in[2];
    const int*   action_keys = (const int*)d_in[3];
    const float* encoded     = (const float*)d_in[4];
    const float* rel_emb     = (const float*)d_in[5];
    float*       out         = (float*)d_out;

    if (ws_size >= WS_NEEDED) {
        ushort* encfrag = (ushort*)((char*)d_ws + WS_ENC_OFF);
        ushort* P2      = (ushort*)((char*)d_ws + WS_P2_OFF);

        hipLaunchKernelGGL(enc_cast, dim3(B), dim3(256), 0, stream,
                           entities, encoded, encfrag);
        hipLaunchKernelGGL(gemm_p2, dim3((RELV + 63) / 64), dim3(256), 0, stream,
                           rel_emb, encfrag, P2);
        hipLaunchKernelGGL(gather_out, dim3(B * K / 256), dim3(256), 0, stream,
                           actions, action_keys, P2, out);
    } else {
        hipLaunchKernelGGL(preds_fused_kernel, dim3(B * CHUNKS), dim3(256), 0, stream,
                           entities, actions, action_keys, encoded, rel_emb, out);
    }
}